// Round 1
// baseline (1327.599 us; speedup 1.0000x reference)
//
#include <hip/hip_runtime.h>
#include <hip/hip_bf16.h>

#define S_LEN 8192
#define DM    1024
#define DK    128
#define BQ    16
#define BK    32
#define DKP4  33   // padded float4 stride (132 floats) to break bank alignment

// ---------------------------------------------------------------------------
// QKV projection: Q|K|V = X @ W{q,k,v}^T, Q pre-scaled by 1/sqrt(DK).
// One block = 16 rows of X staged in LDS (broadcast reads -> conflict free).
// 384 threads = one output column each (cols 0-127 Q, 128-255 K, 256-383 V).
// 16-row register accumulation => each weight row read from global once/block.
// ---------------------------------------------------------------------------
__global__ __launch_bounds__(384, 1)
void qkv_proj_kernel(const float* __restrict__ X,
                     const float* __restrict__ Wq,
                     const float* __restrict__ Wk,
                     const float* __restrict__ Wv,
                     float* __restrict__ QKV) {
    __shared__ float Xs[16 * DM];  // 64 KB
    const int tid = threadIdx.x;
    const int r0  = blockIdx.x * 16;
    {
        const float4* src = (const float4*)(X + (size_t)r0 * DM);
        float4* dst = (float4*)Xs;
        for (int i = tid; i < 16 * DM / 4; i += 384) dst[i] = src[i];
    }
    __syncthreads();

    const int which = tid >> 7;   // 0=Q 1=K 2=V
    const int c     = tid & 127;
    const float* wrow = (which == 0 ? Wq : (which == 1 ? Wk : Wv)) + c * DM;
    const float4* w4 = (const float4*)wrow;

    float4 acc[16];
#pragma unroll
    for (int r = 0; r < 16; ++r) acc[r] = make_float4(0.f, 0.f, 0.f, 0.f);

    for (int k = 0; k < DM / 4; ++k) {
        const float4 wv = w4[k];
        const float4* xcol = (const float4*)Xs + k;
#pragma unroll
        for (int r = 0; r < 16; ++r) {
            const float4 xv = xcol[r * (DM / 4)];   // same addr across lanes: broadcast
            acc[r].x = fmaf(xv.x, wv.x, acc[r].x);
            acc[r].y = fmaf(xv.y, wv.y, acc[r].y);
            acc[r].z = fmaf(xv.z, wv.z, acc[r].z);
            acc[r].w = fmaf(xv.w, wv.w, acc[r].w);
        }
    }

    const float scale = (which == 0) ? 0.088388347648318447f : 1.0f;  // 1/sqrt(128)
    float* outb = QKV + (size_t)which * (S_LEN * DK) + (size_t)r0 * DK + c;
#pragma unroll
    for (int r = 0; r < 16; ++r) {
        const float s = (acc[r].x + acc[r].y) + (acc[r].z + acc[r].w);
        outb[r * DK] = s * scale;
    }
}

// ---------------------------------------------------------------------------
// Flash-style causal attention, fp32. BQ=16 queries/block, BK=32 keys/tile.
// Balanced causal scheduling: block b handles query tiles {b, 511-b} so every
// block does ~257 K-tiles. O accumulator in registers (8 dims/thread).
// ---------------------------------------------------------------------------
__global__ __launch_bounds__(256, 1)
void flash_kernel(const float* __restrict__ QKV, float* __restrict__ Out) {
    const float* Q = QKV;
    const float* K = QKV + S_LEN * DK;
    const float* V = QKV + 2 * S_LEN * DK;

    __shared__ float Qs[BQ * 4 * DKP4];   // 16x132 floats
    __shared__ float Ks[BK * 4 * DKP4];   // 32x132
    __shared__ float Vs[BK * 4 * DKP4];   // 32x132
    __shared__ float Sc[BQ * 33];         // padded score tile
    __shared__ float mS[BQ], lS[BQ], aS[BQ];

    const int tid = threadIdx.x;
    const int row = tid >> 4;          // 0..15: owned O row
    const int dh  = (tid & 15) * 2;    // float4 index of owned 8-dim chunk

    const int nQT = S_LEN / BQ;        // 512 query tiles

    for (int ti = 0; ti < 2; ++ti) {
        const int qt = (ti == 0) ? (int)blockIdx.x : (nQT - 1 - (int)blockIdx.x);
        const int q0 = qt * BQ;

        __syncthreads();  // protect LDS from previous ti iteration
        {
            const float4* srcQ = (const float4*)(Q + (size_t)q0 * DK);
            float4* dq = (float4*)Qs;
            for (int i = tid; i < BQ * DK / 4; i += 256)
                dq[(i >> 5) * DKP4 + (i & 31)] = srcQ[i];
        }
        if (tid < BQ) { mS[tid] = -__builtin_inff(); lS[tid] = 0.f; }

        float4 o0 = make_float4(0.f, 0.f, 0.f, 0.f);
        float4 o1 = make_float4(0.f, 0.f, 0.f, 0.f);

        const int kTiles = qt / 2 + 1;  // last tile index = floor((q0+BQ-1)/BK) = qt/2
        for (int kt = 0; kt < kTiles; ++kt) {
            const int k0 = kt * BK;
            __syncthreads();  // previous PV done before restaging K/V
            {
                const float4* srcK = (const float4*)(K + (size_t)k0 * DK);
                const float4* srcV = (const float4*)(V + (size_t)k0 * DK);
                float4* dk = (float4*)Ks;
                float4* dv = (float4*)Vs;
                for (int i = tid; i < BK * DK / 4; i += 256) {
                    const int a = (i >> 5) * DKP4 + (i & 31);
                    dk[a] = srcK[i];
                    dv[a] = srcV[i];
                }
            }
            __syncthreads();

            // scores: 16x32 dots, 2 per thread
            for (int s = tid; s < BQ * BK; s += 256) {
                const int i = s >> 5, j = s & 31;
                const float4* q4 = (const float4*)Qs + i * DKP4;
                const float4* k4 = (const float4*)Ks + j * DKP4;
                float4 a = make_float4(0.f, 0.f, 0.f, 0.f);
#pragma unroll
                for (int kk = 0; kk < DK / 4; ++kk) {
                    const float4 qv = q4[kk], kv = k4[kk];
                    a.x = fmaf(qv.x, kv.x, a.x);
                    a.y = fmaf(qv.y, kv.y, a.y);
                    a.z = fmaf(qv.z, kv.z, a.z);
                    a.w = fmaf(qv.w, kv.w, a.w);
                }
                float dot = (a.x + a.y) + (a.z + a.w);
                if (k0 + j > q0 + i) dot = -__builtin_inff();
                Sc[i * 33 + j] = dot;
            }
            __syncthreads();

            // online softmax: one thread per query row
            if (tid < BQ) {
                const int i = tid;
                const float mOld = mS[i];
                float rmax = mOld;
#pragma unroll
                for (int j = 0; j < BK; ++j) rmax = fmaxf(rmax, Sc[i * 33 + j]);
                const float alpha = __expf(mOld - rmax);  // mOld=-inf -> 0
                float rsum = 0.f;
#pragma unroll
                for (int j = 0; j < BK; ++j) {
                    const float p = __expf(Sc[i * 33 + j] - rmax);
                    Sc[i * 33 + j] = p;
                    rsum += p;
                }
                mS[i] = rmax;
                lS[i] = lS[i] * alpha + rsum;
                aS[i] = alpha;
            }
            __syncthreads();

            // O update: O = O*alpha + P @ V
            {
                const float alpha = aS[row];
                o0.x *= alpha; o0.y *= alpha; o0.z *= alpha; o0.w *= alpha;
                o1.x *= alpha; o1.y *= alpha; o1.z *= alpha; o1.w *= alpha;
                const float4* v4 = (const float4*)Vs;
#pragma unroll
                for (int j = 0; j < BK; ++j) {
                    const float p = Sc[row * 33 + j];   // broadcast across 16 lanes
                    const float4 va = v4[j * DKP4 + dh];
                    const float4 vb = v4[j * DKP4 + dh + 1];
                    o0.x = fmaf(p, va.x, o0.x); o0.y = fmaf(p, va.y, o0.y);
                    o0.z = fmaf(p, va.z, o0.z); o0.w = fmaf(p, va.w, o0.w);
                    o1.x = fmaf(p, vb.x, o1.x); o1.y = fmaf(p, vb.y, o1.y);
                    o1.z = fmaf(p, vb.z, o1.z); o1.w = fmaf(p, vb.w, o1.w);
                }
            }
        }

        // epilogue: normalize and store
        const float inv = 1.0f / lS[row];
        float4* outp = (float4*)(Out + (size_t)(q0 + row) * DK);
        outp[dh]     = make_float4(o0.x * inv, o0.y * inv, o0.z * inv, o0.w * inv);
        outp[dh + 1] = make_float4(o1.x * inv, o1.y * inv, o1.z * inv, o1.w * inv);
    }
}

extern "C" void kernel_launch(void* const* d_in, const int* in_sizes, int n_in,
                              void* d_out, int out_size, void* d_ws, size_t ws_size,
                              hipStream_t stream) {
    const float* X  = (const float*)d_in[0];
    const float* Wq = (const float*)d_in[1];
    const float* Wk = (const float*)d_in[2];
    const float* Wv = (const float*)d_in[3];
    float* QKV = (float*)d_ws;   // Q | K | V, each S_LEN*DK fp32 (12.6 MB total)
    float* Out = (float*)d_out;

    qkv_proj_kernel<<<S_LEN / 16, 384, 0, stream>>>(X, Wq, Wk, Wv, QKV);
    flash_kernel<<<S_LEN / BQ / 2, 256, 0, stream>>>(QKV, Out);
}

// Round 2
// 490.127 us; speedup vs baseline: 2.7087x; 2.7087x over previous
//
#include <hip/hip_runtime.h>
#include <hip/hip_bf16.h>

#define S_LEN 8192
#define DM    1024
#define DK    128
#define BKK   128    // keys per K-tile in flash
#define NW    8      // waves per flash block
#define PSTR  136    // P LDS row stride in bf16 (2-way max bank aliasing)

typedef __attribute__((ext_vector_type(8))) short bf16x8;
typedef __attribute__((ext_vector_type(4))) float f32x4;

__device__ __forceinline__ f32x4 mfma16(bf16x8 a, bf16x8 b, f32x4 c) {
    return __builtin_amdgcn_mfma_f32_16x16x32_bf16(a, b, c, 0, 0, 0);
}

// fp32 -> bf16 (RNE), bit-exact, no API dependence
__device__ __forceinline__ ushort f2bf(float f) {
    unsigned u = __builtin_bit_cast(unsigned, f);
    u += 0x7FFFu + ((u >> 16) & 1u);
    return (ushort)(u >> 16);
}

// ---------------------------------------------------------------------------
// QKV projection (fp32 VALU, bf16 outputs).
// Q pre-scaled by 1/sqrt(128)*log2(e) (flash softmax runs in exp2 domain).
// V written TRANSPOSED (Vt[dim][seq]) so PV B-frags are contiguous.
// ---------------------------------------------------------------------------
__global__ __launch_bounds__(384, 1)
void qkv_proj_kernel(const float* __restrict__ X,
                     const float* __restrict__ Wq,
                     const float* __restrict__ Wk,
                     const float* __restrict__ Wv,
                     ushort* __restrict__ Qb,
                     ushort* __restrict__ Kb,
                     ushort* __restrict__ Vtb) {
    __shared__ float Xs[16 * DM];  // 64 KB
    const int tid = threadIdx.x;
    const int r0  = blockIdx.x * 16;
    {
        const float4* src = (const float4*)(X + (size_t)r0 * DM);
        float4* dst = (float4*)Xs;
        for (int i = tid; i < 16 * DM / 4; i += 384) dst[i] = src[i];
    }
    __syncthreads();

    const int which = tid >> 7;   // 0=Q 1=K 2=V
    const int c     = tid & 127;
    const float* wrow = (which == 0 ? Wq : (which == 1 ? Wk : Wv)) + c * DM;
    const float4* w4 = (const float4*)wrow;

    float4 acc[16];
#pragma unroll
    for (int r = 0; r < 16; ++r) acc[r] = make_float4(0.f, 0.f, 0.f, 0.f);

    for (int k = 0; k < DM / 4; ++k) {
        const float4 wv = w4[k];
        const float4* xcol = (const float4*)Xs + k;
#pragma unroll
        for (int r = 0; r < 16; ++r) {
            const float4 xv = xcol[r * (DM / 4)];   // broadcast across lanes
            acc[r].x = fmaf(xv.x, wv.x, acc[r].x);
            acc[r].y = fmaf(xv.y, wv.y, acc[r].y);
            acc[r].z = fmaf(xv.z, wv.z, acc[r].z);
            acc[r].w = fmaf(xv.w, wv.w, acc[r].w);
        }
    }

    float s[16];
#pragma unroll
    for (int r = 0; r < 16; ++r)
        s[r] = (acc[r].x + acc[r].y) + (acc[r].z + acc[r].w);

    if (which == 0) {
        const float qs = 0.088388347648318447f * 1.4426950408889634f;
#pragma unroll
        for (int r = 0; r < 16; ++r) Qb[(size_t)(r0 + r) * DK + c] = f2bf(s[r] * qs);
    } else if (which == 1) {
#pragma unroll
        for (int r = 0; r < 16; ++r) Kb[(size_t)(r0 + r) * DK + c] = f2bf(s[r]);
    } else {
        uint* dst = (uint*)(Vtb + (size_t)c * S_LEN + r0);  // 16 contiguous bf16
#pragma unroll
        for (int r = 0; r < 16; r += 2)
            dst[r >> 1] = (uint)f2bf(s[r]) | ((uint)f2bf(s[r + 1]) << 16);
    }
}

// ---------------------------------------------------------------------------
// MFMA flash attention, causal. 256 blocks x 8 waves.
// Block b handles Q-tiles {b, 511-b} (16 rows each) -> balanced work.
// Split-K inside block: wave w takes K-tiles w, w+8, ... (128 keys each),
// private (m,l,O) in registers; merged at the end via LDS float atomics.
// K/Vt fragments read directly from global (L2-resident, no cross-wave reuse).
// ---------------------------------------------------------------------------
__global__ __launch_bounds__(512, 2)
void flash_kernel(const ushort* __restrict__ Qg,
                  const ushort* __restrict__ Kg,
                  const ushort* __restrict__ Vtg,
                  float* __restrict__ Out) {
    __shared__ __align__(16) ushort Plds[NW * 16 * PSTR];  // 34.8 KB
    __shared__ __align__(16) float mergeO[16 * 132];       // 8.4 KB
    __shared__ float mergeL[16];
    __shared__ float mlbuf[NW][16][2];

    const int tid  = threadIdx.x;
    const int wv   = tid >> 6;
    const int lane = tid & 63;
    const int quad = lane >> 4;
    const int l15  = lane & 15;
    ushort* Pl = Plds + wv * 16 * PSTR;

    for (int ti = 0; ti < 2; ++ti) {
        const int qt  = ti ? (511 - (int)blockIdx.x) : (int)blockIdx.x;
        const int q0  = qt * 16;
        const int nkt = (q0 + 16 + BKK - 1) >> 7;   // ceil((q0+16)/128)

        __syncthreads();   // protect previous phase's merge reads
        for (int i = tid; i < 16 * 132; i += 512) mergeO[i] = 0.f;
        if (tid < 16) mergeL[tid] = 0.f;

        // Q fragments (A-operand layout), resident all phase
        bf16x8 qf[4];
        {
            const ushort* qrow = Qg + (size_t)(q0 + l15) * DK + quad * 8;
#pragma unroll
            for (int kc = 0; kc < 4; ++kc) qf[kc] = *(const bf16x8*)(qrow + kc * 32);
        }

        float m_[4], l_[4];
#pragma unroll
        for (int r = 0; r < 4; ++r) { m_[r] = -__builtin_inff(); l_[r] = 0.f; }
        f32x4 acc[8];
#pragma unroll
        for (int d = 0; d < 8; ++d) acc[d] = (f32x4){0.f, 0.f, 0.f, 0.f};

        for (int kt = wv; kt < nkt; kt += NW) {
            const int k0 = kt << 7;

            // ---- scores S = Q K^T (16 x 128), C layout ----
            f32x4 Sr[8];
#pragma unroll
            for (int nb = 0; nb < 8; ++nb) {
                Sr[nb] = (f32x4){0.f, 0.f, 0.f, 0.f};
                const ushort* krow = Kg + (size_t)(k0 + nb * 16 + l15) * DK + quad * 8;
#pragma unroll
                for (int kc = 0; kc < 4; ++kc)
                    Sr[nb] = mfma16(qf[kc], *(const bf16x8*)(krow + kc * 32), Sr[nb]);
            }

            // ---- causal mask (diagonal tile only) ----
            if (k0 + BKK - 1 > q0) {
#pragma unroll
                for (int nb = 0; nb < 8; ++nb) {
                    const int kg = k0 + nb * 16 + l15;
#pragma unroll
                    for (int r = 0; r < 4; ++r)
                        if (kg > q0 + quad * 4 + r) Sr[nb][r] = -__builtin_inff();
                }
            }

            // ---- online softmax (exp2 domain; scale folded into Q) ----
            float al[4], rs[4];
#pragma unroll
            for (int r = 0; r < 4; ++r) {
                float v = m_[r];
#pragma unroll
                for (int nb = 0; nb < 8; ++nb) v = fmaxf(v, Sr[nb][r]);
                v = fmaxf(v, __shfl_xor(v, 1));
                v = fmaxf(v, __shfl_xor(v, 2));
                v = fmaxf(v, __shfl_xor(v, 4));
                v = fmaxf(v, __shfl_xor(v, 8));
                al[r] = exp2f(m_[r] - v);   // m=-inf first tile -> 0
                m_[r] = v;
                rs[r] = 0.f;
            }
#pragma unroll
            for (int nb = 0; nb < 8; ++nb) {
#pragma unroll
                for (int r = 0; r < 4; ++r) {
                    const float p = exp2f(Sr[nb][r] - m_[r]);
                    rs[r] += p;
                    Pl[(quad * 4 + r) * PSTR + nb * 16 + l15] = f2bf(p);
                }
            }
#pragma unroll
            for (int r = 0; r < 4; ++r) {
                float v = rs[r];
                v += __shfl_xor(v, 1);
                v += __shfl_xor(v, 2);
                v += __shfl_xor(v, 4);
                v += __shfl_xor(v, 8);
                l_[r] = l_[r] * al[r] + v;
            }
#pragma unroll
            for (int d = 0; d < 8; ++d)
#pragma unroll
                for (int r = 0; r < 4; ++r) acc[d][r] *= al[r];

            // ---- O += P V  (P via LDS round-trip to A layout) ----
#pragma unroll
            for (int kcp = 0; kcp < 4; ++kcp) {
                const bf16x8 pf = *(const bf16x8*)(Pl + l15 * PSTR + kcp * 32 + quad * 8);
#pragma unroll
                for (int db = 0; db < 8; ++db) {
                    const bf16x8 vf = *(const bf16x8*)(Vtg + (size_t)(db * 16 + l15) * S_LEN
                                                       + k0 + kcp * 32 + quad * 8);
                    acc[db] = mfma16(pf, vf, acc[db]);
                }
            }
        }

        // ---- merge the 8 per-wave partials ----
        if (l15 == 0) {
#pragma unroll
            for (int r = 0; r < 4; ++r) {
                mlbuf[wv][quad * 4 + r][0] = m_[r];
                mlbuf[wv][quad * 4 + r][1] = l_[r];
            }
        }
        __syncthreads();   // zeros + mlbuf complete

#pragma unroll
        for (int r = 0; r < 4; ++r) {
            const int row = quad * 4 + r;
            float M = mlbuf[0][row][0];
#pragma unroll
            for (int w = 1; w < NW; ++w) M = fmaxf(M, mlbuf[w][row][0]);
            const float be = exp2f(m_[r] - M);   // 0 for idle waves
            if (l15 == 0) atomicAdd(&mergeL[row], l_[r] * be);
#pragma unroll
            for (int d = 0; d < 8; ++d)
                atomicAdd(&mergeO[row * 132 + d * 16 + l15], acc[d][r] * be);
        }
        __syncthreads();

        // ---- normalize + store (512 threads x 4 floats = 16x128) ----
        {
            const int row = tid >> 5, c4 = tid & 31;
            const f32x4 v = *(const f32x4*)&mergeO[row * 132 + c4 * 4];
            const float inv = 1.0f / mergeL[row];
            float4 o;
            o.x = v[0] * inv; o.y = v[1] * inv; o.z = v[2] * inv; o.w = v[3] * inv;
            *(float4*)(Out + (size_t)(q0 + row) * DK + c4 * 4) = o;
        }
    }
}

extern "C" void kernel_launch(void* const* d_in, const int* in_sizes, int n_in,
                              void* d_out, int out_size, void* d_ws, size_t ws_size,
                              hipStream_t stream) {
    const float* X  = (const float*)d_in[0];
    const float* Wq = (const float*)d_in[1];
    const float* Wk = (const float*)d_in[2];
    const float* Wv = (const float*)d_in[3];
    ushort* ws  = (ushort*)d_ws;
    ushort* Qb  = ws;                        // 8192x128 bf16, pre-scaled
    ushort* Kb  = ws + (size_t)S_LEN * DK;   // 8192x128 bf16
    ushort* Vtb = ws + 2 * (size_t)S_LEN * DK; // 128x8192 bf16 (transposed)
    float* Out = (float*)d_out;

    qkv_proj_kernel<<<S_LEN / 16, 384, 0, stream>>>(X, Wq, Wk, Wv, Qb, Kb, Vtb);
    flash_kernel<<<256, 512, 0, stream>>>(Qb, Kb, Vtb, Out);
}

// Round 3
// 284.790 us; speedup vs baseline: 4.6617x; 1.7210x over previous
//
#include <hip/hip_runtime.h>
#include <hip/hip_bf16.h>

#define S_LEN 8192
#define DM    1024
#define DK    128
#define BKK   128    // keys per K-tile in flash
#define NW    8      // waves per flash block
#define PSTR  136    // P LDS row stride in bf16 (2-way max bank aliasing)

typedef __attribute__((ext_vector_type(8))) short bf16x8;
typedef __attribute__((ext_vector_type(8))) _Float16 f16x8;
typedef __attribute__((ext_vector_type(4))) float f32x4;

__device__ __forceinline__ f32x4 mfma16(bf16x8 a, bf16x8 b, f32x4 c) {
    return __builtin_amdgcn_mfma_f32_16x16x32_bf16(a, b, c, 0, 0, 0);
}

// fp32 -> bf16 (RNE)
__device__ __forceinline__ ushort f2bf(float f) {
    unsigned u = __builtin_bit_cast(unsigned, f);
    u += 0x7FFFu + ((u >> 16) & 1u);
    return (ushort)(u >> 16);
}

// ---------------------------------------------------------------------------
// fp32 -> fp16 conversion of X (8192x1024) and Wq|Wk|Wv (each 128x1024).
// ---------------------------------------------------------------------------
__global__ __launch_bounds__(256, 1)
void convert_kernel(const float* __restrict__ X,
                    const float* __restrict__ Wq,
                    const float* __restrict__ Wk,
                    const float* __restrict__ Wv,
                    _Float16* __restrict__ Xh,
                    _Float16* __restrict__ Wh) {
    const int NX4 = S_LEN * DM / 4;   // 2097152
    const int NW4 = DK * DM / 4;      // 32768 per weight
    const int total4 = NX4 + 3 * NW4;
    for (int i = blockIdx.x * 256 + threadIdx.x; i < total4; i += gridDim.x * 256) {
        const float4* src;
        _Float16* dst;
        int off;
        if (i < NX4) {
            src = (const float4*)X; dst = Xh; off = i;
        } else {
            const int w = i - NX4;
            const int which = w / NW4;
            off = w - which * NW4;
            src = (const float4*)(which == 0 ? Wq : (which == 1 ? Wk : Wv));
            dst = Wh + which * (DK * DM);
        }
        const float4 v = src[off];
        union { _Float16 h[4]; uint2 u; } p;
        p.h[0] = (_Float16)v.x; p.h[1] = (_Float16)v.y;
        p.h[2] = (_Float16)v.z; p.h[3] = (_Float16)v.w;
        *(uint2*)(dst + (size_t)off * 4) = p.u;
    }
}

// ---------------------------------------------------------------------------
// Projection GEMM (fp16 MFMA): C[8192x384] = Xh[8192x1024] @ Wh^T.
// m97 structure: BM=BN=128, BK=32, 256 thr / 4 waves (2x2, 64x64 each, 4x4 acc),
// global_load_lds width-16 staging, 16 MFMA : 8 ds_read_b128 per k-iter.
// blockIdx.y picks the output head: 0=Q (scaled, bf16), 1=K (bf16),
// 2=V (bf16, TRANSPOSED to Vt[dim][seq]).
// ---------------------------------------------------------------------------
__global__ __launch_bounds__(256)
void proj_gemm_kernel(const _Float16* __restrict__ Xh,
                      const _Float16* __restrict__ Wh,
                      ushort* __restrict__ Qb,
                      ushort* __restrict__ Kb,
                      ushort* __restrict__ Vtb) {
    __shared__ _Float16 Ash[128 * 32];   // 8 KB
    __shared__ _Float16 Bsh[128 * 32];   // 8 KB

    const int tid  = threadIdx.x;
    const int lane = tid & 63;
    const int quad = lane >> 4;
    const int l15  = lane & 15;
    const int wv   = tid >> 6;
    const int wm   = wv & 1;
    const int wn   = wv >> 1;
    const int m0   = blockIdx.x * 128;
    const int nb   = blockIdx.y;          // 0=Q 1=K 2=V
    const _Float16* Wbase = Wh + nb * (DK * DM);

    f32x4 acc[4][4];
#pragma unroll
    for (int mi = 0; mi < 4; ++mi)
#pragma unroll
        for (int ni = 0; ni < 4; ++ni) acc[mi][ni] = (f32x4){0.f, 0.f, 0.f, 0.f};

    for (int kk = 0; kk < DM; kk += 32) {
        __syncthreads();   // previous iter's frag reads complete
#pragma unroll
        for (int s = tid; s < 512; s += 256) {
            const int row = s >> 2, sg = s & 3;
            __builtin_amdgcn_global_load_lds(
                (const __attribute__((address_space(1))) void*)(Xh + (size_t)(m0 + row) * DM + kk + sg * 8),
                (__attribute__((address_space(3))) void*)(Ash + s * 8), 16, 0, 0);
            __builtin_amdgcn_global_load_lds(
                (const __attribute__((address_space(1))) void*)(Wbase + (size_t)row * DM + kk + sg * 8),
                (__attribute__((address_space(3))) void*)(Bsh + s * 8), 16, 0, 0);
        }
        __syncthreads();   // staging complete (vmcnt drained before barrier)

        f16x8 af[4], bf[4];
#pragma unroll
        for (int t = 0; t < 4; ++t) {
            af[t] = *(const f16x8*)(Ash + (wm * 64 + t * 16 + l15) * 32 + quad * 8);
            bf[t] = *(const f16x8*)(Bsh + (wn * 64 + t * 16 + l15) * 32 + quad * 8);
        }
#pragma unroll
        for (int mi = 0; mi < 4; ++mi)
#pragma unroll
            for (int ni = 0; ni < 4; ++ni)
                acc[mi][ni] = __builtin_amdgcn_mfma_f32_16x16x32_f16(af[mi], bf[ni], acc[mi][ni], 0, 0, 0);
    }

    // epilogue: C/D layout col=l15, row=quad*4+reg
    if (nb == 2) {
#pragma unroll
        for (int mi = 0; mi < 4; ++mi)
#pragma unroll
            for (int ni = 0; ni < 4; ++ni) {
                const int n = wn * 64 + ni * 16 + l15;             // dim
                const int m = m0 + wm * 64 + mi * 16 + quad * 4;   // seq base
                union { ushort h[4]; uint2 u; } p;
#pragma unroll
                for (int r = 0; r < 4; ++r) p.h[r] = f2bf(acc[mi][ni][r]);
                *(uint2*)(Vtb + (size_t)n * S_LEN + m) = p.u;
            }
    } else {
        ushort* Ob = (nb == 0) ? Qb : Kb;
        const float sc = (nb == 0) ? 0.088388347648318447f * 1.4426950408889634f : 1.0f;
#pragma unroll
        for (int mi = 0; mi < 4; ++mi)
#pragma unroll
            for (int ni = 0; ni < 4; ++ni) {
                const int n = wn * 64 + ni * 16 + l15;
#pragma unroll
                for (int r = 0; r < 4; ++r) {
                    const int m = m0 + wm * 64 + mi * 16 + quad * 4 + r;
                    Ob[(size_t)m * DK + n] = f2bf(acc[mi][ni][r] * sc);
                }
            }
    }
}

// ---------------------------------------------------------------------------
// MFMA flash attention, causal (unchanged from round 2).
// ---------------------------------------------------------------------------
__global__ __launch_bounds__(512, 2)
void flash_kernel(const ushort* __restrict__ Qg,
                  const ushort* __restrict__ Kg,
                  const ushort* __restrict__ Vtg,
                  float* __restrict__ Out) {
    __shared__ __align__(16) ushort Plds[NW * 16 * PSTR];
    __shared__ __align__(16) float mergeO[16 * 132];
    __shared__ float mergeL[16];
    __shared__ float mlbuf[NW][16][2];

    const int tid  = threadIdx.x;
    const int wv   = tid >> 6;
    const int lane = tid & 63;
    const int quad = lane >> 4;
    const int l15  = lane & 15;
    ushort* Pl = Plds + wv * 16 * PSTR;

    for (int ti = 0; ti < 2; ++ti) {
        const int qt  = ti ? (511 - (int)blockIdx.x) : (int)blockIdx.x;
        const int q0  = qt * 16;
        const int nkt = (q0 + 16 + BKK - 1) >> 7;

        __syncthreads();
        for (int i = tid; i < 16 * 132; i += 512) mergeO[i] = 0.f;
        if (tid < 16) mergeL[tid] = 0.f;

        bf16x8 qf[4];
        {
            const ushort* qrow = Qg + (size_t)(q0 + l15) * DK + quad * 8;
#pragma unroll
            for (int kc = 0; kc < 4; ++kc) qf[kc] = *(const bf16x8*)(qrow + kc * 32);
        }

        float m_[4], l_[4];
#pragma unroll
        for (int r = 0; r < 4; ++r) { m_[r] = -__builtin_inff(); l_[r] = 0.f; }
        f32x4 acc[8];
#pragma unroll
        for (int d = 0; d < 8; ++d) acc[d] = (f32x4){0.f, 0.f, 0.f, 0.f};

        for (int kt = wv; kt < nkt; kt += NW) {
            const int k0 = kt << 7;

            f32x4 Sr[8];
#pragma unroll
            for (int nb = 0; nb < 8; ++nb) {
                Sr[nb] = (f32x4){0.f, 0.f, 0.f, 0.f};
                const ushort* krow = Kg + (size_t)(k0 + nb * 16 + l15) * DK + quad * 8;
#pragma unroll
                for (int kc = 0; kc < 4; ++kc)
                    Sr[nb] = mfma16(qf[kc], *(const bf16x8*)(krow + kc * 32), Sr[nb]);
            }

            if (k0 + BKK - 1 > q0) {
#pragma unroll
                for (int nb = 0; nb < 8; ++nb) {
                    const int kg = k0 + nb * 16 + l15;
#pragma unroll
                    for (int r = 0; r < 4; ++r)
                        if (kg > q0 + quad * 4 + r) Sr[nb][r] = -__builtin_inff();
                }
            }

            float al[4], rs[4];
#pragma unroll
            for (int r = 0; r < 4; ++r) {
                float v = m_[r];
#pragma unroll
                for (int nb = 0; nb < 8; ++nb) v = fmaxf(v, Sr[nb][r]);
                v = fmaxf(v, __shfl_xor(v, 1));
                v = fmaxf(v, __shfl_xor(v, 2));
                v = fmaxf(v, __shfl_xor(v, 4));
                v = fmaxf(v, __shfl_xor(v, 8));
                al[r] = exp2f(m_[r] - v);
                m_[r] = v;
                rs[r] = 0.f;
            }
#pragma unroll
            for (int nb = 0; nb < 8; ++nb) {
#pragma unroll
                for (int r = 0; r < 4; ++r) {
                    const float p = exp2f(Sr[nb][r] - m_[r]);
                    rs[r] += p;
                    Pl[(quad * 4 + r) * PSTR + nb * 16 + l15] = f2bf(p);
                }
            }
#pragma unroll
            for (int r = 0; r < 4; ++r) {
                float v = rs[r];
                v += __shfl_xor(v, 1);
                v += __shfl_xor(v, 2);
                v += __shfl_xor(v, 4);
                v += __shfl_xor(v, 8);
                l_[r] = l_[r] * al[r] + v;
            }
#pragma unroll
            for (int d = 0; d < 8; ++d)
#pragma unroll
                for (int r = 0; r < 4; ++r) acc[d][r] *= al[r];

#pragma unroll
            for (int kcp = 0; kcp < 4; ++kcp) {
                const bf16x8 pf = *(const bf16x8*)(Pl + l15 * PSTR + kcp * 32 + quad * 8);
#pragma unroll
                for (int db = 0; db < 8; ++db) {
                    const bf16x8 vf = *(const bf16x8*)(Vtg + (size_t)(db * 16 + l15) * S_LEN
                                                       + k0 + kcp * 32 + quad * 8);
                    acc[db] = mfma16(pf, vf, acc[db]);
                }
            }
        }

        if (l15 == 0) {
#pragma unroll
            for (int r = 0; r < 4; ++r) {
                mlbuf[wv][quad * 4 + r][0] = m_[r];
                mlbuf[wv][quad * 4 + r][1] = l_[r];
            }
        }
        __syncthreads();

#pragma unroll
        for (int r = 0; r < 4; ++r) {
            const int row = quad * 4 + r;
            float M = mlbuf[0][row][0];
#pragma unroll
            for (int w = 1; w < NW; ++w) M = fmaxf(M, mlbuf[w][row][0]);
            const float be = exp2f(m_[r] - M);
            if (l15 == 0) atomicAdd(&mergeL[row], l_[r] * be);
#pragma unroll
            for (int d = 0; d < 8; ++d)
                atomicAdd(&mergeO[row * 132 + d * 16 + l15], acc[d][r] * be);
        }
        __syncthreads();

        {
            const int row = tid >> 5, c4 = tid & 31;
            const f32x4 v = *(const f32x4*)&mergeO[row * 132 + c4 * 4];
            const float inv = 1.0f / mergeL[row];
            float4 o;
            o.x = v[0] * inv; o.y = v[1] * inv; o.z = v[2] * inv; o.w = v[3] * inv;
            *(float4*)(Out + (size_t)(q0 + row) * DK + c4 * 4) = o;
        }
    }
}

extern "C" void kernel_launch(void* const* d_in, const int* in_sizes, int n_in,
                              void* d_out, int out_size, void* d_ws, size_t ws_size,
                              hipStream_t stream) {
    const float* X  = (const float*)d_in[0];
    const float* Wq = (const float*)d_in[1];
    const float* Wk = (const float*)d_in[2];
    const float* Wv = (const float*)d_in[3];
    ushort* ws  = (ushort*)d_ws;
    ushort* Qb  = ws;                          // 8192x128 bf16 (pre-scaled)
    ushort* Kb  = ws + (size_t)S_LEN * DK;     // 8192x128 bf16
    ushort* Vtb = ws + 2 * (size_t)S_LEN * DK; // 128x8192 bf16 (transposed)
    _Float16* Xh = (_Float16*)(ws + 3 * (size_t)S_LEN * DK);  // 8192x1024 fp16
    _Float16* Wh = Xh + (size_t)S_LEN * DM;                   // 384x1024 fp16
    float* Out = (float*)d_out;

    convert_kernel<<<1024, 256, 0, stream>>>(X, Wq, Wk, Wv, Xh, Wh);
    proj_gemm_kernel<<<dim3(64, 3), 256, 0, stream>>>(Xh, Wh, Qb, Kb, Vtb);
    flash_kernel<<<256, 512, 0, stream>>>(Qb, Kb, Vtb, Out);
}